// Round 2
// baseline (405.990 us; speedup 1.0000x reference)
//
#include <hip/hip_runtime.h>
#include <hip/hip_bf16.h>
#include <math.h>

typedef __bf16 bf16x8 __attribute__((ext_vector_type(8)));
typedef __bf16 bf16x4 __attribute__((ext_vector_type(4)));
typedef float  f32x4  __attribute__((ext_vector_type(4)));
typedef short  s16x8  __attribute__((ext_vector_type(8)));

#define N_TOK  4096
#define DMODEL 1024
#define NHEAD  4
#define DHEAD  256

__device__ __forceinline__ f32x4 mfma16x16(bf16x8 a, bf16x8 b, f32x4 c) {
    return __builtin_amdgcn_mfma_f32_16x16x32_bf16(a, b, c, 0, 0, 0);
}

// async global->LDS, 16B per lane; LDS dest = wave-uniform base + lane*16
__device__ __forceinline__ void gload_lds16(const void* gsrc, void* ldst) {
    __builtin_amdgcn_global_load_lds(
        (const __attribute__((address_space(1))) void*)gsrc,
        (__attribute__((address_space(3))) void*)ldst, 16, 0, 0);
}

// ---- weight transpose+convert: in [R][C] fp32 -> out [C][R] bf16
__global__ __launch_bounds__(256)
void transposew_kernel(const float* __restrict__ in, __bf16* __restrict__ out,
                       int R, int C)
{
    __shared__ __align__(16) __bf16 tile[64 * 72];
    const int tid = threadIdx.x;
    const int r0 = blockIdx.x * 64;
    const int c0 = blockIdx.y * 64;
    #pragma unroll
    for (int it = 0; it < 4; ++it) {
        int i = tid + it * 256;          // 64 rows x 16 quarters
        int row = i >> 4, c4 = i & 15;
        f32x4 v = *(const f32x4*)(in + (size_t)(r0 + row) * C + c0 + c4 * 4);
        #pragma unroll
        for (int j = 0; j < 4; ++j)
            tile[(c4 * 4 + j) * 72 + row] = (__bf16)v[j];
    }
    __syncthreads();
    #pragma unroll
    for (int it = 0; it < 2; ++it) {
        int i = tid + it * 256;          // 64 cols x 8 chunks
        int col = i >> 3, ch = i & 7;
        s16x8 v = *(const s16x8*)(&tile[col * 72 + ch * 8]);
        *(s16x8*)((short*)out + (size_t)(c0 + col) * R + r0 + ch * 8) = v;
    }
}

// ---- bt-GEMM: C[M,N] = (A[M,K] @ B[N,K]^T + bias) * scale (, relu, rowmask)
// A: fp32 (AF32) via VGPR cvt staging, or bf16 via global_load_lds.
// B: fp32 (BF32) via VGPR cvt staging, or bf16 via global_load_lds.
// LDS: linear rows of 64 bf16 (128B = 8 x 16B chunks), chunk c of row r stored
// at slot c ^ (r&7); gload_lds sources pre-swizzled (involution, rule #21).
// Tile BM=128, BN=64, BK=64; 4 waves in 2x2; wave tile 64x32.
template<typename OutT, bool AF32, bool BF32, bool BIASROW>
__global__ __launch_bounds__(256, 2)
void gemm_bt(const void* __restrict__ Av, int lda,
             const void* __restrict__ Bv, int ldb,
             const float* __restrict__ bias,
             OutT* __restrict__ C, int ldc,
             float scale, int relu, const float* __restrict__ rowmask, int K)
{
    __shared__ __align__(16) short As[128 * 64];   // 16 KB
    __shared__ __align__(16) short Bs[64 * 64];    //  8 KB
    const int tid  = threadIdx.x;
    const int lane = tid & 63;
    const int wv   = tid >> 6;
    const int c16  = lane & 15;
    const int quad = lane >> 4;
    const int swz  = c16 & 7;
    const int wr   = wv >> 1;    // 0..1  (64-row half)
    const int wc   = wv & 1;     // 0..1  (32-col half)
    const int m0 = blockIdx.x * 128;
    const int n0 = blockIdx.y * 64;

    f32x4 acc[4][2];
    #pragma unroll
    for (int i = 0; i < 4; ++i)
        #pragma unroll
        for (int j = 0; j < 2; ++j)
            acc[i][j] = (f32x4){0.f, 0.f, 0.f, 0.f};

    // staging lane geometry for gload_lds paths (8 rows x 8 chunks per instr)
    const int sRow = lane >> 3;                     // 0..7
    const int sCh  = (lane & 7) ^ (sRow & 7);       // pre-swizzled chunk

    #pragma unroll 1
    for (int k0 = 0; k0 < K; k0 += 64) {
        // ---- stage A tile [128 rows][64 k]
        if (AF32) {
            const float* A = (const float*)Av;
            #pragma unroll
            for (int r = 0; r < 4; ++r) {
                int idx = tid + r * 256;            // 128 rows x 8 chunks
                int row = idx >> 3, ch = idx & 7;
                const float* ap = A + (size_t)(m0 + row) * lda + k0 + ch * 8;
                f32x4 t0 = *(const f32x4*)ap;
                f32x4 t1 = *(const f32x4*)(ap + 4);
                bf16x8 b;
                #pragma unroll
                for (int j = 0; j < 4; ++j) { b[j] = (__bf16)t0[j]; b[j + 4] = (__bf16)t1[j]; }
                *(bf16x8*)((char*)As + row * 128 + ((ch ^ (row & 7)) * 16)) = b;
            }
        } else {
            const __bf16* A = (const __bf16*)Av;
            #pragma unroll
            for (int g = 0; g < 4; ++g) {           // wave wv: rows [32wv, 32wv+32)
                int row = 32 * wv + 8 * g + sRow;
                const char* src = (const char*)(A + (size_t)(m0 + row) * lda + k0) + sCh * 16;
                gload_lds16(src, (char*)As + (32 * wv + 8 * g) * 128);
            }
        }
        // ---- stage B tile [64 rows][64 k]
        if (BF32) {
            const float* B = (const float*)Bv;
            #pragma unroll
            for (int r = 0; r < 2; ++r) {
                int idx = tid + r * 256;            // 64 rows x 8 chunks
                int row = idx >> 3, ch = idx & 7;
                const float* bp = B + (size_t)(n0 + row) * ldb + k0 + ch * 8;
                f32x4 t0 = *(const f32x4*)bp;
                f32x4 t1 = *(const f32x4*)(bp + 4);
                bf16x8 b;
                #pragma unroll
                for (int j = 0; j < 4; ++j) { b[j] = (__bf16)t0[j]; b[j + 4] = (__bf16)t1[j]; }
                *(bf16x8*)((char*)Bs + row * 128 + ((ch ^ (row & 7)) * 16)) = b;
            }
        } else {
            const __bf16* B = (const __bf16*)Bv;
            #pragma unroll
            for (int g = 0; g < 2; ++g) {           // wave wv: rows [16wv, 16wv+16)
                int row = 16 * wv + 8 * g + sRow;
                const char* src = (const char*)(B + (size_t)(n0 + row) * ldb + k0) + sCh * 16;
                gload_lds16(src, (char*)Bs + (16 * wv + 8 * g) * 128);
            }
        }
        __syncthreads();

        __builtin_amdgcn_s_setprio(1);
        #pragma unroll
        for (int ks = 0; ks < 2; ++ks) {
            bf16x8 af[4], bfr[2];
            int slot = ((ks * 4 + quad) ^ swz) * 16;
            #pragma unroll
            for (int t = 0; t < 4; ++t)
                af[t] = *(const bf16x8*)((char*)As + (wr * 64 + t * 16 + c16) * 128 + slot);
            #pragma unroll
            for (int t = 0; t < 2; ++t)
                bfr[t] = *(const bf16x8*)((char*)Bs + (wc * 32 + t * 16 + c16) * 128 + slot);
            #pragma unroll
            for (int tm = 0; tm < 4; ++tm)
                #pragma unroll
                for (int tn = 0; tn < 2; ++tn)
                    acc[tm][tn] = mfma16x16(af[tm], bfr[tn], acc[tm][tn]);
        }
        __builtin_amdgcn_s_setprio(0);
        __syncthreads();
    }

    #pragma unroll
    for (int tm = 0; tm < 4; ++tm) {
        #pragma unroll
        for (int rr = 0; rr < 4; ++rr) {
            int row = m0 + wr * 64 + tm * 16 + quad * 4 + rr;
            float mk = rowmask ? rowmask[row] : 1.0f;
            float rb = BIASROW ? bias[row] : 0.0f;
            #pragma unroll
            for (int tn = 0; tn < 2; ++tn) {
                int col = n0 + wc * 32 + tn * 16 + c16;
                float b = BIASROW ? rb : bias[col];
                float val = (acc[tm][tn][rr] + b) * scale;
                if (relu) val = fmaxf(val, 0.0f);
                val *= mk;
                C[(size_t)row * ldc + col] = (OutT)val;
            }
        }
    }
}

// ---- scores -> mask (unchanged)
__global__ void score_mask_kernel(const __bf16* __restrict__ h,
                                  const float* __restrict__ w2,
                                  const float* __restrict__ b2,
                                  float* __restrict__ maskf)
{
    int lane = threadIdx.x & 63;
    int tok  = blockIdx.x * 4 + (threadIdx.x >> 6);
    const __bf16* hr = h + (size_t)tok * 256;
    float s = 0.f;
    #pragma unroll
    for (int j = 0; j < 4; ++j) {
        int c = j * 64 + lane;
        s += (float)hr[c] * w2[c];
    }
    #pragma unroll
    for (int o = 1; o < 64; o <<= 1) s += __shfl_xor(s, o);
    if (lane == 0) {
        float x = s + b2[0];
        maskf[tok] = (x > -1.7346010553881064f) ? 1.0f : 0.0f;
    }
}

// ---- flash attention (unchanged from R1: swizzled LDS + gload_lds staging)
template<bool SPLIT>
__global__ __launch_bounds__(256, 2)
void attn_kernel(const __bf16* __restrict__ qp, const __bf16* __restrict__ kp,
                 const __bf16* __restrict__ vpT, const float* __restrict__ maskf,
                 __bf16* __restrict__ O0, __bf16* __restrict__ O1,
                 float* __restrict__ lbuf)
{
    __shared__ __align__(16) short Ks[64 * 256];    // 32 KB
    __shared__ __align__(16) short Vs[256 * 64];    // 32 KB
    __shared__ __align__(16) short PsA[4 * 16 * 64]; // 8 KB

    const int tid  = threadIdx.x;
    const int lane = tid & 63;
    const int wv   = tid >> 6;
    const int c16  = lane & 15;
    const int quad = lane >> 4;
    const int swz  = c16 & 7;
    const int head = blockIdx.y;
    const int ksp  = SPLIT ? blockIdx.z : 0;
    const int kbase = ksp * (SPLIT ? 2048 : 0);
    const int kend  = kbase + (SPLIT ? 2048 : 4096);
    const int q0   = blockIdx.x * 64 + wv * 16;
    short* Ps = PsA + wv * 16 * 64;
    __bf16* Ob = (SPLIT && ksp == 1) ? O1 : O0;

    bf16x8 qf[8];
    #pragma unroll
    for (int c = 0; c < 8; ++c)
        qf[c] = *(const bf16x8*)(qp + (size_t)(q0 + c16) * DMODEL + head * DHEAD + c * 32 + quad * 8);

    f32x4 o[16];
    #pragma unroll
    for (int t = 0; t < 16; ++t) o[t] = (f32x4){0.f, 0.f, 0.f, 0.f};
    float psum[4] = {0.f, 0.f, 0.f, 0.f};

    const int kRow0 = wv * 16 + (lane >> 5);
    const int kCh   = lane & 31;
    const int vRow0 = wv * 64 + (lane >> 3);
    const int vCh   = (lane & 7) ^ ((lane >> 3) & 7);

    #pragma unroll 1
    for (int n0 = kbase; n0 < kend; n0 += 64) {
        #pragma unroll
        for (int g = 0; g < 8; ++g) {
            int key = kRow0 + g * 2;
            int c   = kCh ^ (key & 7);
            const char* src = (const char*)(kp + (size_t)(n0 + key) * DMODEL + head * DHEAD) + c * 16;
            gload_lds16(src, (char*)Ks + (wv * 16 + g * 2) * 512);
        }
        #pragma unroll
        for (int g = 0; g < 8; ++g) {
            int row = vRow0 + g * 8;
            const char* src = (const char*)(vpT + (size_t)(head * DHEAD + row) * N_TOK + n0) + vCh * 16;
            gload_lds16(src, (char*)Vs + (wv * 64 + g * 8) * 128);
        }
        __syncthreads();

        f32x4 s[4];
        #pragma unroll
        for (int kt = 0; kt < 4; ++kt) s[kt] = (f32x4){0.f, 0.f, 0.f, 0.f};
        __builtin_amdgcn_s_setprio(1);
        #pragma unroll
        for (int c = 0; c < 8; ++c)
            #pragma unroll
            for (int kt = 0; kt < 4; ++kt) {
                bf16x8 bfr = *(const bf16x8*)(&Ks[(kt * 16 + c16) * 256 + (((c * 4 + quad) ^ swz) << 3)]);
                s[kt] = mfma16x16(qf[c], bfr, s[kt]);
            }
        __builtin_amdgcn_s_setprio(0);

        #pragma unroll
        for (int kt = 0; kt < 4; ++kt) {
            float biasv = (maskf[n0 + kt * 16 + c16] - 1.0f) * 1e9f;
            #pragma unroll
            for (int r = 0; r < 4; ++r) {
                float p = __expf(s[kt][r] + biasv);
                psum[r] += p;
                int qrow = quad * 4 + r;
                int ch = (kt * 2 + (c16 >> 3)) ^ (qrow & 7);
                *(__bf16*)&Ps[qrow * 64 + ch * 8 + swz] = (__bf16)p;
            }
        }

        __builtin_amdgcn_s_waitcnt(0xc07f);  // lgkmcnt(0)

        __builtin_amdgcn_s_setprio(1);
        #pragma unroll
        for (int kstep = 0; kstep < 2; ++kstep) {
            bf16x8 pf = *(const bf16x8*)(&Ps[c16 * 64 + (((kstep * 4 + quad) ^ swz) << 3)]);
            #pragma unroll
            for (int t = 0; t < 16; ++t) {
                bf16x8 vf = *(const bf16x8*)(&Vs[(t * 16 + c16) * 64 + (((kstep * 4 + quad) ^ swz) << 3)]);
                o[t] = mfma16x16(pf, vf, o[t]);
            }
        }
        __builtin_amdgcn_s_setprio(0);
        __syncthreads();
    }

    float inv[4];
    #pragma unroll
    for (int r = 0; r < 4; ++r) {
        float t = psum[r];
        t += __shfl_xor(t, 1);
        t += __shfl_xor(t, 2);
        t += __shfl_xor(t, 4);
        t += __shfl_xor(t, 8);
        if (SPLIT && c16 == 0)
            lbuf[(size_t)(ksp * NHEAD + head) * N_TOK + q0 + quad * 4 + r] = t;
        inv[r] = 1.0f / t;
    }
    #pragma unroll
    for (int t = 0; t < 16; ++t)
        #pragma unroll
        for (int r = 0; r < 4; ++r) {
            float val = o[t][r] * inv[r];
            Ob[(size_t)(q0 + quad * 4 + r) * DMODEL + head * DHEAD + t * 16 + c16] = (__bf16)val;
        }
}

// ---- combine (unchanged)
__global__ void combine_kernel(const __bf16* __restrict__ O0,
                               const __bf16* __restrict__ O1,
                               const float* __restrict__ lbuf,
                               __bf16* __restrict__ out)
{
    int idx  = blockIdx.x * 256 + threadIdx.x;
    int tok  = idx >> 7;
    int g    = idx & 127;
    int head = g >> 5;
    float a = lbuf[(size_t)head * N_TOK + tok];
    float b = lbuf[(size_t)(NHEAD + head) * N_TOK + tok];
    float w0 = a / (a + b);
    float w1 = 1.0f - w0;
    size_t off = (size_t)tok * DMODEL + g * 8;
    bf16x8 x = *(const bf16x8*)(O0 + off);
    bf16x8 y = *(const bf16x8*)(O1 + off);
    bf16x8 z;
    #pragma unroll
    for (int j = 0; j < 8; ++j) z[j] = (__bf16)(w0 * (float)x[j] + w1 * (float)y[j]);
    *(bf16x8*)(out + off) = z;
}

extern "C" void kernel_launch(void* const* d_in, const int* in_sizes, int n_in,
                              void* d_out, int out_size, void* d_ws, size_t ws_size,
                              hipStream_t stream)
{
    (void)in_sizes; (void)n_in; (void)out_size;
    const float* q  = (const float*)d_in[0];
    const float* k  = (const float*)d_in[1];
    const float* v  = (const float*)d_in[2];
    const float* w1 = (const float*)d_in[3];
    const float* b1 = (const float*)d_in[4];
    const float* w2 = (const float*)d_in[5];
    const float* b2 = (const float*)d_in[6];
    const float* wq = (const float*)d_in[7];
    const float* bq = (const float*)d_in[8];
    const float* wk = (const float*)d_in[9];
    const float* bk = (const float*)d_in[10];
    const float* wvw = (const float*)d_in[11];
    const float* bv = (const float*)d_in[12];
    const float* wo = (const float*)d_in[13];
    const float* bo = (const float*)d_in[14];

    if (ws_size < 35667968u) return;  // proven floor

    char* ws = (char*)d_ws;
    float*  maskf = (float*)ws;                       // 16 KB
    __bf16* hbuf  = (__bf16*)(ws + 16384);            // 4096x256 bf16 = 2 MB; reused as woT after score_mask
    __bf16* qp    = (__bf16*)(ws + 16384 + 2097152);  // 8 MB each
    __bf16* kpb   = qp  + 4194304;
    __bf16* vpT   = kpb + 4194304;                    // [1024][4096] bf16, written directly by swapped V-gemm
    __bf16* ctx   = vpT + 4194304;                    // also O0 in split path
    __bf16* O1    = (__bf16*)(ws + 35667968u);        // 8 MB
    float*  lbuf  = (float*)(ws + 35667968u + 8388608u);
    const bool split = ws_size >= 35667968u + 8388608u + 131072u;

    // d_out (16 MB fp32) doubles as scratch for transposed weights; all dead
    // before the final out-proj GEMM overwrites d_out (stream-ordered).
    __bf16* wqT = (__bf16*)d_out;                 // [1024][1024] bf16, 2 MB
    __bf16* wkT = wqT + 1048576;
    __bf16* wvT = wkT + 1048576;
    __bf16* w1T = wvT + 1048576;                  // [256][1024] bf16, 0.5 MB
    __bf16* woT = hbuf;                           // reuses hbuf after score_mask

    // 1) w1^T, then h = relu(q@w1+b1), then mask
    transposew_kernel<<<dim3(16, 4), 256, 0, stream>>>(w1, w1T, 1024, 256);
    gemm_bt<__bf16, true, false, false><<<dim3(32, 4), 256, 0, stream>>>(
        q, 1024, w1T, 1024, b1, hbuf, 256, 1.0f, 1, nullptr, 1024);
    score_mask_kernel<<<1024, 256, 0, stream>>>(hbuf, w2, b2, maskf);

    // 2) transpose remaining weights (hbuf free now -> woT)
    transposew_kernel<<<dim3(16, 16), 256, 0, stream>>>(wq, wqT, 1024, 1024);
    transposew_kernel<<<dim3(16, 16), 256, 0, stream>>>(wk, wkT, 1024, 1024);
    transposew_kernel<<<dim3(16, 16), 256, 0, stream>>>(wvw, wvT, 1024, 1024);
    transposew_kernel<<<dim3(16, 16), 256, 0, stream>>>(wo, woT, 1024, 1024);

    // 3) projections: qp = (q@wq)*1/16, kp = k@wk; vpT = (v@wv)^T via operand swap
    gemm_bt<__bf16, true, false, false><<<dim3(32, 16), 256, 0, stream>>>(
        q, 1024, wqT, 1024, bq, qp, 1024, 0.0625f, 0, nullptr, 1024);
    gemm_bt<__bf16, true, false, false><<<dim3(32, 16), 256, 0, stream>>>(
        k, 1024, wkT, 1024, bk, kpb, 1024, 1.0f, 0, nullptr, 1024);
    gemm_bt<__bf16, false, true, true><<<dim3(8, 64), 256, 0, stream>>>(
        wvT, 1024, v, 1024, bv, vpT, 4096, 1.0f, 0, nullptr, 1024);

    // 4) attention
    if (split) {
        attn_kernel<true><<<dim3(64, 4, 2), 256, 0, stream>>>(qp, kpb, vpT, maskf, ctx, O1, lbuf);
        combine_kernel<<<2048, 256, 0, stream>>>(ctx, O1, lbuf, ctx);
    } else {
        attn_kernel<false><<<dim3(64, 4, 1), 256, 0, stream>>>(qp, kpb, vpT, maskf, ctx, nullptr, nullptr);
    }

    // 5) out-projection (A = ctx bf16 via gload_lds, B = woT bf16)
    gemm_bt<float, false, false, false><<<dim3(32, 16), 256, 0, stream>>>(
        ctx, 1024, woT, 1024, bo, (float*)d_out, 1024, 1.0f, 0, maskf, 1024);
}

// Round 3
// 346.793 us; speedup vs baseline: 1.1707x; 1.1707x over previous
//
#include <hip/hip_runtime.h>
#include <hip/hip_bf16.h>
#include <math.h>

typedef __bf16 bf16x8 __attribute__((ext_vector_type(8)));
typedef __bf16 bf16x4 __attribute__((ext_vector_type(4)));
typedef float  f32x4  __attribute__((ext_vector_type(4)));
typedef short  s16x8  __attribute__((ext_vector_type(8)));

#define N_TOK  4096
#define DMODEL 1024
#define NHEAD  4
#define DHEAD  256

__device__ __forceinline__ f32x4 mfma16x16(bf16x8 a, bf16x8 b, f32x4 c) {
    return __builtin_amdgcn_mfma_f32_16x16x32_bf16(a, b, c, 0, 0, 0);
}

// async global->LDS, 16B per lane; LDS dest = wave-uniform base + lane*16
__device__ __forceinline__ void gload_lds16(const void* gsrc, void* ldst) {
    __builtin_amdgcn_global_load_lds(
        (const __attribute__((address_space(1))) void*)gsrc,
        (__attribute__((address_space(3))) void*)ldst, 16, 0, 0);
}

// ---- weight transpose+convert: in [R][C] fp32 -> out [C][R] bf16
__global__ __launch_bounds__(256)
void transposew_kernel(const float* __restrict__ in, __bf16* __restrict__ out,
                       int R, int C)
{
    __shared__ __align__(16) __bf16 tile[64 * 72];
    const int tid = threadIdx.x;
    const int r0 = blockIdx.x * 64;
    const int c0 = blockIdx.y * 64;
    #pragma unroll
    for (int it = 0; it < 4; ++it) {
        int i = tid + it * 256;          // 64 rows x 16 quarters
        int row = i >> 4, c4 = i & 15;
        f32x4 v = *(const f32x4*)(in + (size_t)(r0 + row) * C + c0 + c4 * 4);
        #pragma unroll
        for (int j = 0; j < 4; ++j)
            tile[(c4 * 4 + j) * 72 + row] = (__bf16)v[j];
    }
    __syncthreads();
    #pragma unroll
    for (int it = 0; it < 2; ++it) {
        int i = tid + it * 256;          // 64 cols x 8 chunks
        int col = i >> 3, ch = i & 7;
        s16x8 v = *(const s16x8*)(&tile[col * 72 + ch * 8]);
        *(s16x8*)((short*)out + (size_t)(c0 + col) * R + r0 + ch * 8) = v;
    }
}

// ---- bt-GEMM, DOUBLE-BUFFERED 2-phase: C[M,N] = (A[M,K] @ B[N,K]^T + bias)*scale
// Per tile: issue next-tile loads -> MFMA on current buffer -> cvt+ds_write of
// staged fp32 regs -> ONE __syncthreads() (drains gloads + ds_writes).
// LDS rows 64 bf16 (128B = 8 chunks), chunk c of row r at slot c^(r&7).
// Tile BM=128, BN=64, BK=64; 4 waves in 2x2; wave tile 64x32.
template<typename OutT, bool AF32, bool BF32, bool BIASROW>
__global__ __launch_bounds__(256, 2)
void gemm_bt(const void* __restrict__ Av, int lda,
             const void* __restrict__ Bv, int ldb,
             const float* __restrict__ bias,
             OutT* __restrict__ C, int ldc,
             float scale, int relu, const float* __restrict__ rowmask, int K)
{
    __shared__ __align__(16) short As[2][128 * 64];   // 32 KB
    __shared__ __align__(16) short Bs[2][64 * 64];    // 16 KB
    const int tid  = threadIdx.x;
    const int lane = tid & 63;
    const int wv   = tid >> 6;
    const int c16  = lane & 15;
    const int quad = lane >> 4;
    const int swz  = c16 & 7;
    const int wr   = wv >> 1;
    const int wc   = wv & 1;
    const int m0 = blockIdx.x * 128;
    const int n0 = blockIdx.y * 64;

    f32x4 acc[4][2];
    #pragma unroll
    for (int i = 0; i < 4; ++i)
        #pragma unroll
        for (int j = 0; j < 2; ++j)
            acc[i][j] = (f32x4){0.f, 0.f, 0.f, 0.f};

    // staged fp32 regs (held across the MFMA phase)
    f32x4 ra[8], rb[4];

    const int sRow = lane >> 3;                     // gload geometry: 8 rows x 8 chunks
    const int sCh  = (lane & 7) ^ (sRow & 7);

    auto a_issue = [&](short* Abuf, int k0) {
        if (AF32) {
            const float* A = (const float*)Av;
            #pragma unroll
            for (int r = 0; r < 4; ++r) {
                int idx = tid + r * 256;            // 128 rows x 8 chunks
                int row = idx >> 3, ch = idx & 7;
                const float* ap = A + (size_t)(m0 + row) * lda + k0 + ch * 8;
                ra[2 * r]     = *(const f32x4*)ap;
                ra[2 * r + 1] = *(const f32x4*)(ap + 4);
            }
        } else {
            const __bf16* A = (const __bf16*)Av;
            #pragma unroll
            for (int g = 0; g < 4; ++g) {
                int row = 32 * wv + 8 * g + sRow;
                const char* src = (const char*)(A + (size_t)(m0 + row) * lda + k0) + sCh * 16;
                gload_lds16(src, (char*)Abuf + (32 * wv + 8 * g) * 128);
            }
        }
    };
    auto a_write = [&](short* Abuf) {
        if (AF32) {
            #pragma unroll
            for (int r = 0; r < 4; ++r) {
                int idx = tid + r * 256;
                int row = idx >> 3, ch = idx & 7;
                bf16x8 b;
                #pragma unroll
                for (int j = 0; j < 4; ++j) { b[j] = (__bf16)ra[2 * r][j]; b[j + 4] = (__bf16)ra[2 * r + 1][j]; }
                *(bf16x8*)((char*)Abuf + row * 128 + ((ch ^ (row & 7)) * 16)) = b;
            }
        }
    };
    auto b_issue = [&](short* Bbuf, int k0) {
        if (BF32) {
            const float* B = (const float*)Bv;
            #pragma unroll
            for (int r = 0; r < 2; ++r) {
                int idx = tid + r * 256;            // 64 rows x 8 chunks
                int row = idx >> 3, ch = idx & 7;
                const float* bp = B + (size_t)(n0 + row) * ldb + k0 + ch * 8;
                rb[2 * r]     = *(const f32x4*)bp;
                rb[2 * r + 1] = *(const f32x4*)(bp + 4);
            }
        } else {
            const __bf16* B = (const __bf16*)Bv;
            #pragma unroll
            for (int g = 0; g < 2; ++g) {
                int row = 16 * wv + 8 * g + sRow;
                const char* src = (const char*)(B + (size_t)(n0 + row) * ldb + k0) + sCh * 16;
                gload_lds16(src, (char*)Bbuf + (16 * wv + 8 * g) * 128);
            }
        }
    };
    auto b_write = [&](short* Bbuf) {
        if (BF32) {
            #pragma unroll
            for (int r = 0; r < 2; ++r) {
                int idx = tid + r * 256;
                int row = idx >> 3, ch = idx & 7;
                bf16x8 b;
                #pragma unroll
                for (int j = 0; j < 4; ++j) { b[j] = (__bf16)rb[2 * r][j]; b[j + 4] = (__bf16)rb[2 * r + 1][j]; }
                *(bf16x8*)((char*)Bbuf + row * 128 + ((ch ^ (row & 7)) * 16)) = b;
            }
        }
    };
    auto compute = [&](const short* Abuf, const short* Bbuf) {
        __builtin_amdgcn_s_setprio(1);
        #pragma unroll
        for (int ks = 0; ks < 2; ++ks) {
            bf16x8 af[4], bfr[2];
            int slot = ((ks * 4 + quad) ^ swz) * 16;
            #pragma unroll
            for (int t = 0; t < 4; ++t)
                af[t] = *(const bf16x8*)((const char*)Abuf + (wr * 64 + t * 16 + c16) * 128 + slot);
            #pragma unroll
            for (int t = 0; t < 2; ++t)
                bfr[t] = *(const bf16x8*)((const char*)Bbuf + (wc * 32 + t * 16 + c16) * 128 + slot);
            #pragma unroll
            for (int tm = 0; tm < 4; ++tm)
                #pragma unroll
                for (int tn = 0; tn < 2; ++tn)
                    acc[tm][tn] = mfma16x16(af[tm], bfr[tn], acc[tm][tn]);
        }
        __builtin_amdgcn_s_setprio(0);
    };

    const int nt = K >> 6;   // always 16 here (even)
    a_issue(As[0], 0); b_issue(Bs[0], 0);
    a_write(As[0]);    b_write(Bs[0]);
    __syncthreads();

    #pragma unroll 1
    for (int t = 0; t < nt; t += 2) {
        // phase A: compute buf0, stage tile t+1 into buf1
        if (t + 1 < nt) { a_issue(As[1], (t + 1) << 6); b_issue(Bs[1], (t + 1) << 6); }
        compute(As[0], Bs[0]);
        if (t + 1 < nt) { a_write(As[1]); b_write(Bs[1]); }
        __syncthreads();
        // phase B: compute buf1, stage tile t+2 into buf0
        if (t + 1 < nt) {
            if (t + 2 < nt) { a_issue(As[0], (t + 2) << 6); b_issue(Bs[0], (t + 2) << 6); }
            compute(As[1], Bs[1]);
            if (t + 2 < nt) { a_write(As[0]); b_write(Bs[0]); }
            __syncthreads();
        }
    }

    #pragma unroll
    for (int tm = 0; tm < 4; ++tm) {
        #pragma unroll
        for (int rr = 0; rr < 4; ++rr) {
            int row = m0 + wr * 64 + tm * 16 + quad * 4 + rr;
            float mk = rowmask ? rowmask[row] : 1.0f;
            float rbv = BIASROW ? bias[row] : 0.0f;
            #pragma unroll
            for (int tn = 0; tn < 2; ++tn) {
                int col = n0 + wc * 32 + tn * 16 + c16;
                float b = BIASROW ? rbv : bias[col];
                float val = (acc[tm][tn][rr] + b) * scale;
                if (relu) val = fmaxf(val, 0.0f);
                val *= mk;
                C[(size_t)row * ldc + col] = (OutT)val;
            }
        }
    }
}

// ---- scores -> mask (unchanged)
__global__ void score_mask_kernel(const __bf16* __restrict__ h,
                                  const float* __restrict__ w2,
                                  const float* __restrict__ b2,
                                  float* __restrict__ maskf)
{
    int lane = threadIdx.x & 63;
    int tok  = blockIdx.x * 4 + (threadIdx.x >> 6);
    const __bf16* hr = h + (size_t)tok * 256;
    float s = 0.f;
    #pragma unroll
    for (int j = 0; j < 4; ++j) {
        int c = j * 64 + lane;
        s += (float)hr[c] * w2[c];
    }
    #pragma unroll
    for (int o = 1; o < 64; o <<= 1) s += __shfl_xor(s, o);
    if (lane == 0) {
        float x = s + b2[0];
        maskf[tok] = (x > -1.7346010553881064f) ? 1.0f : 0.0f;
    }
}

// ---- flash attention (R1 structure). SPLIT path: flattened grid with
// XCD-clustering remap so all 64 blocks of one (head,ksp) group share one
// XCD's L2 (K 1MB + V 1MB + qp slice 2MB = 4MB = L2). d%8 = XCD (round-robin).
template<bool SPLIT>
__global__ __launch_bounds__(256, 2)
void attn_kernel(const __bf16* __restrict__ qp, const __bf16* __restrict__ kp,
                 const __bf16* __restrict__ vpT, const float* __restrict__ maskf,
                 __bf16* __restrict__ O0, __bf16* __restrict__ O1,
                 float* __restrict__ lbuf)
{
    __shared__ __align__(16) short Ks[64 * 256];    // 32 KB
    __shared__ __align__(16) short Vs[256 * 64];    // 32 KB
    __shared__ __align__(16) short PsA[4 * 16 * 64]; // 8 KB

    const int tid  = threadIdx.x;
    const int lane = tid & 63;
    const int wv   = tid >> 6;
    const int c16  = lane & 15;
    const int quad = lane >> 4;
    const int swz  = c16 & 7;

    int qb, head, ksp;
    if (SPLIT) {
        int d    = blockIdx.x;                 // 0..511, XCD = d & 7
        int orig = ((d & 7) << 6) | (d >> 3);  // bijective: group g = d&7 on XCD g
        qb   = orig & 63;
        head = (orig >> 6) & 3;
        ksp  = orig >> 8;
    } else {
        qb = blockIdx.x; head = blockIdx.y; ksp = 0;
    }
    const int kbase = ksp * (SPLIT ? 2048 : 0);
    const int kend  = kbase + (SPLIT ? 2048 : 4096);
    const int q0   = qb * 64 + wv * 16;
    short* Ps = PsA + wv * 16 * 64;
    __bf16* Ob = (SPLIT && ksp == 1) ? O1 : O0;

    bf16x8 qf[8];
    #pragma unroll
    for (int c = 0; c < 8; ++c)
        qf[c] = *(const bf16x8*)(qp + (size_t)(q0 + c16) * DMODEL + head * DHEAD + c * 32 + quad * 8);

    f32x4 o[16];
    #pragma unroll
    for (int t = 0; t < 16; ++t) o[t] = (f32x4){0.f, 0.f, 0.f, 0.f};
    float psum[4] = {0.f, 0.f, 0.f, 0.f};

    const int kRow0 = wv * 16 + (lane >> 5);
    const int kCh   = lane & 31;
    const int vRow0 = wv * 64 + (lane >> 3);
    const int vCh   = (lane & 7) ^ ((lane >> 3) & 7);

    #pragma unroll 1
    for (int n0 = kbase; n0 < kend; n0 += 64) {
        #pragma unroll
        for (int g = 0; g < 8; ++g) {
            int key = kRow0 + g * 2;
            int c   = kCh ^ (key & 7);
            const char* src = (const char*)(kp + (size_t)(n0 + key) * DMODEL + head * DHEAD) + c * 16;
            gload_lds16(src, (char*)Ks + (wv * 16 + g * 2) * 512);
        }
        #pragma unroll
        for (int g = 0; g < 8; ++g) {
            int row = vRow0 + g * 8;
            const char* src = (const char*)(vpT + (size_t)(head * DHEAD + row) * N_TOK + n0) + vCh * 16;
            gload_lds16(src, (char*)Vs + (wv * 64 + g * 8) * 128);
        }
        __syncthreads();

        f32x4 s[4];
        #pragma unroll
        for (int kt = 0; kt < 4; ++kt) s[kt] = (f32x4){0.f, 0.f, 0.f, 0.f};
        __builtin_amdgcn_s_setprio(1);
        #pragma unroll
        for (int c = 0; c < 8; ++c)
            #pragma unroll
            for (int kt = 0; kt < 4; ++kt) {
                bf16x8 bfr = *(const bf16x8*)(&Ks[(kt * 16 + c16) * 256 + (((c * 4 + quad) ^ swz) << 3)]);
                s[kt] = mfma16x16(qf[c], bfr, s[kt]);
            }
        __builtin_amdgcn_s_setprio(0);

        #pragma unroll
        for (int kt = 0; kt < 4; ++kt) {
            float biasv = (maskf[n0 + kt * 16 + c16] - 1.0f) * 1e9f;
            #pragma unroll
            for (int r = 0; r < 4; ++r) {
                float p = __expf(s[kt][r] + biasv);
                psum[r] += p;
                int qrow = quad * 4 + r;
                int ch = (kt * 2 + (c16 >> 3)) ^ (qrow & 7);
                *(__bf16*)&Ps[qrow * 64 + ch * 8 + swz] = (__bf16)p;
            }
        }

        __builtin_amdgcn_s_waitcnt(0xc07f);  // lgkmcnt(0)

        __builtin_amdgcn_s_setprio(1);
        #pragma unroll
        for (int kstep = 0; kstep < 2; ++kstep) {
            bf16x8 pf = *(const bf16x8*)(&Ps[c16 * 64 + (((kstep * 4 + quad) ^ swz) << 3)]);
            #pragma unroll
            for (int t = 0; t < 16; ++t) {
                bf16x8 vf = *(const bf16x8*)(&Vs[(t * 16 + c16) * 64 + (((kstep * 4 + quad) ^ swz) << 3)]);
                o[t] = mfma16x16(pf, vf, o[t]);
            }
        }
        __builtin_amdgcn_s_setprio(0);
        __syncthreads();
    }

    float inv[4];
    #pragma unroll
    for (int r = 0; r < 4; ++r) {
        float t = psum[r];
        t += __shfl_xor(t, 1);
        t += __shfl_xor(t, 2);
        t += __shfl_xor(t, 4);
        t += __shfl_xor(t, 8);
        if (SPLIT && c16 == 0)
            lbuf[(size_t)(ksp * NHEAD + head) * N_TOK + q0 + quad * 4 + r] = t;
        inv[r] = 1.0f / t;
    }
    #pragma unroll
    for (int t = 0; t < 16; ++t)
        #pragma unroll
        for (int r = 0; r < 4; ++r) {
            float val = o[t][r] * inv[r];
            Ob[(size_t)(q0 + quad * 4 + r) * DMODEL + head * DHEAD + t * 16 + c16] = (__bf16)val;
        }
}

// ---- combine (unchanged)
__global__ void combine_kernel(const __bf16* __restrict__ O0,
                               const __bf16* __restrict__ O1,
                               const float* __restrict__ lbuf,
                               __bf16* __restrict__ out)
{
    int idx  = blockIdx.x * 256 + threadIdx.x;
    int tok  = idx >> 7;
    int g    = idx & 127;
    int head = g >> 5;
    float a = lbuf[(size_t)head * N_TOK + tok];
    float b = lbuf[(size_t)(NHEAD + head) * N_TOK + tok];
    float w0 = a / (a + b);
    float w1 = 1.0f - w0;
    size_t off = (size_t)tok * DMODEL + g * 8;
    bf16x8 x = *(const bf16x8*)(O0 + off);
    bf16x8 y = *(const bf16x8*)(O1 + off);
    bf16x8 z;
    #pragma unroll
    for (int j = 0; j < 8; ++j) z[j] = (__bf16)(w0 * (float)x[j] + w1 * (float)y[j]);
    *(bf16x8*)(out + off) = z;
}

extern "C" void kernel_launch(void* const* d_in, const int* in_sizes, int n_in,
                              void* d_out, int out_size, void* d_ws, size_t ws_size,
                              hipStream_t stream)
{
    (void)in_sizes; (void)n_in; (void)out_size;
    const float* q  = (const float*)d_in[0];
    const float* k  = (const float*)d_in[1];
    const float* v  = (const float*)d_in[2];
    const float* w1 = (const float*)d_in[3];
    const float* b1 = (const float*)d_in[4];
    const float* w2 = (const float*)d_in[5];
    const float* b2 = (const float*)d_in[6];
    const float* wq = (const float*)d_in[7];
    const float* bq = (const float*)d_in[8];
    const float* wk = (const float*)d_in[9];
    const float* bk = (const float*)d_in[10];
    const float* wvw = (const float*)d_in[11];
    const float* bv = (const float*)d_in[12];
    const float* wo = (const float*)d_in[13];
    const float* bo = (const float*)d_in[14];

    if (ws_size < 35667968u) return;  // proven floor

    char* ws = (char*)d_ws;
    float*  maskf = (float*)ws;                       // 16 KB
    __bf16* hbuf  = (__bf16*)(ws + 16384);            // 2 MB; reused as woT after score_mask
    __bf16* qp    = (__bf16*)(ws + 16384 + 2097152);  // 8 MB each
    __bf16* kpb   = qp  + 4194304;
    __bf16* vpT   = kpb + 4194304;                    // [1024][4096] bf16 via swapped V-gemm
    __bf16* ctx   = vpT + 4194304;                    // also O0 in split path
    __bf16* O1    = (__bf16*)(ws + 35667968u);        // 8 MB
    float*  lbuf  = (float*)(ws + 35667968u + 8388608u);
    const bool split = ws_size >= 35667968u + 8388608u + 131072u;

    // d_out (16 MB fp32) doubles as scratch for transposed weights; all dead
    // before the final out-proj GEMM overwrites d_out (stream-ordered).
    __bf16* wqT = (__bf16*)d_out;                 // [1024][1024] bf16, 2 MB
    __bf16* wkT = wqT + 1048576;
    __bf16* wvT = wkT + 1048576;
    __bf16* w1T = wvT + 1048576;                  // [256][1024] bf16, 0.5 MB
    __bf16* woT = hbuf;                           // reuses hbuf after score_mask

    // 1) w1^T, then h = relu(q@w1+b1), then mask
    transposew_kernel<<<dim3(16, 4), 256, 0, stream>>>(w1, w1T, 1024, 256);
    gemm_bt<__bf16, true, false, false><<<dim3(32, 4), 256, 0, stream>>>(
        q, 1024, w1T, 1024, b1, hbuf, 256, 1.0f, 1, nullptr, 1024);
    score_mask_kernel<<<1024, 256, 0, stream>>>(hbuf, w2, b2, maskf);

    // 2) transpose remaining weights (hbuf free now -> woT)
    transposew_kernel<<<dim3(16, 16), 256, 0, stream>>>(wq, wqT, 1024, 1024);
    transposew_kernel<<<dim3(16, 16), 256, 0, stream>>>(wk, wkT, 1024, 1024);
    transposew_kernel<<<dim3(16, 16), 256, 0, stream>>>(wvw, wvT, 1024, 1024);
    transposew_kernel<<<dim3(16, 16), 256, 0, stream>>>(wo, woT, 1024, 1024);

    // 3) projections: qp = (q@wq)*1/16, kp = k@wk; vpT = (v@wv)^T via operand swap
    gemm_bt<__bf16, true, false, false><<<dim3(32, 16), 256, 0, stream>>>(
        q, 1024, wqT, 1024, bq, qp, 1024, 0.0625f, 0, nullptr, 1024);
    gemm_bt<__bf16, true, false, false><<<dim3(32, 16), 256, 0, stream>>>(
        k, 1024, wkT, 1024, bk, kpb, 1024, 1.0f, 0, nullptr, 1024);
    gemm_bt<__bf16, false, true, true><<<dim3(8, 64), 256, 0, stream>>>(
        wvT, 1024, v, 1024, bv, vpT, 4096, 1.0f, 0, nullptr, 1024);

    // 4) attention (flattened grid + XCD-clustering remap)
    if (split) {
        attn_kernel<true><<<dim3(512, 1, 1), 256, 0, stream>>>(qp, kpb, vpT, maskf, ctx, O1, lbuf);
        combine_kernel<<<2048, 256, 0, stream>>>(ctx, O1, lbuf, ctx);
    } else {
        attn_kernel<false><<<dim3(64, 4, 1), 256, 0, stream>>>(qp, kpb, vpT, maskf, ctx, nullptr, nullptr);
    }

    // 5) out-projection (A = ctx bf16 via gload_lds, B = woT bf16)
    gemm_bt<float, false, false, false><<<dim3(32, 16), 256, 0, stream>>>(
        ctx, 1024, woT, 1024, bo, (float*)d_out, 1024, 1.0f, 0, maskf, 1024);
}

// Round 5
// 324.478 us; speedup vs baseline: 1.2512x; 1.0688x over previous
//
#include <hip/hip_runtime.h>
#include <hip/hip_bf16.h>
#include <math.h>

typedef __bf16 bf16x8 __attribute__((ext_vector_type(8)));
typedef __bf16 bf16x4 __attribute__((ext_vector_type(4)));
typedef float  f32x4  __attribute__((ext_vector_type(4)));
typedef short  s16x8  __attribute__((ext_vector_type(8)));

#define N_TOK  4096
#define DMODEL 1024
#define NHEAD  4
#define DHEAD  256

__device__ __forceinline__ f32x4 mfma16x16(bf16x8 a, bf16x8 b, f32x4 c) {
    return __builtin_amdgcn_mfma_f32_16x16x32_bf16(a, b, c, 0, 0, 0);
}

// async global->LDS, 16B per lane; LDS dest = wave-uniform base + lane*16
__device__ __forceinline__ void gload_lds16(const void* gsrc, void* ldst) {
    __builtin_amdgcn_global_load_lds(
        (const __attribute__((address_space(1))) void*)gsrc,
        (__attribute__((address_space(3))) void*)ldst, 16, 0, 0);
}

// ---- batched fp32 -> bf16 convert (q,k,v), 8 elem/thread
struct CvtArgs { const float* src[3]; __bf16* dst[3]; };
__global__ __launch_bounds__(256)
void cvt_bf16_kernel(CvtArgs a)
{
    const float* in = a.src[blockIdx.y];
    __bf16* out = a.dst[blockIdx.y];
    size_t i8 = ((size_t)blockIdx.x * 256 + threadIdx.x) * 8;
    f32x4 t0 = *(const f32x4*)(in + i8);
    f32x4 t1 = *(const f32x4*)(in + i8 + 4);
    bf16x8 b;
    #pragma unroll
    for (int j = 0; j < 4; ++j) { b[j] = (__bf16)t0[j]; b[j + 4] = (__bf16)t1[j]; }
    *(bf16x8*)(out + i8) = b;
}

// ---- weight transpose+convert: in [1024][C] fp32 -> out [C][1024] bf16
__device__ __forceinline__ void transposew_body(const float* __restrict__ in,
                                                __bf16* __restrict__ out, int C)
{
    __shared__ __align__(16) __bf16 tile[64 * 72];
    const int tid = threadIdx.x;
    const int r0 = blockIdx.x * 64;
    const int c0 = blockIdx.y * 64;
    if (c0 >= C) return;
    #pragma unroll
    for (int it = 0; it < 4; ++it) {
        int i = tid + it * 256;          // 64 rows x 16 quarters
        int row = i >> 4, c4 = i & 15;
        f32x4 v = *(const f32x4*)(in + (size_t)(r0 + row) * C + c0 + c4 * 4);
        #pragma unroll
        for (int j = 0; j < 4; ++j)
            tile[(c4 * 4 + j) * 72 + row] = (__bf16)v[j];
    }
    __syncthreads();
    #pragma unroll
    for (int it = 0; it < 2; ++it) {
        int i = tid + it * 256;          // 64 cols x 8 chunks
        int col = i >> 3, ch = i & 7;
        s16x8 v = *(const s16x8*)(&tile[col * 72 + ch * 8]);
        *(s16x8*)((short*)out + (size_t)(c0 + col) * 1024 + r0 + ch * 8) = v;
    }
}

__global__ __launch_bounds__(256)
void transposew_kernel(const float* __restrict__ in, __bf16* __restrict__ out, int C)
{
    transposew_body(in, out, C);
}

struct TWArgs { const float* src[4]; __bf16* dst[4]; int C[4]; };
__global__ __launch_bounds__(256)
void transposew_batch_kernel(TWArgs a)
{
    int z = blockIdx.z;
    transposew_body(a.src[z], a.dst[z], a.C[z]);
}

// ---- bt-GEMM, all-bf16, DOUBLE-BUFFERED 2-phase via global_load_lds:
// C[M,N] = (A[M,K] @ B[N,K]^T + bias) * scale (, relu, rowmask)
// LDS rows 64 bf16 (128B = 8 chunks), chunk c of row r at slot c^(r&7);
// gload sources pre-swizzled (involution). BM=128,BN=64,BK=64; 4 waves 2x2.
template<typename OutT, bool BIASROW>
__global__ __launch_bounds__(256, 2)
void gemm_bt(const __bf16* __restrict__ A, int lda,
             const __bf16* __restrict__ B, int ldb,
             const float* __restrict__ bias,
             OutT* __restrict__ C, int ldc,
             float scale, int relu, const float* __restrict__ rowmask, int K)
{
    __shared__ __align__(16) short As[2][128 * 64];   // 32 KB
    __shared__ __align__(16) short Bs[2][64 * 64];    // 16 KB
    const int tid  = threadIdx.x;
    const int lane = tid & 63;
    const int wv   = tid >> 6;
    const int c16  = lane & 15;
    const int quad = lane >> 4;
    const int swz  = c16 & 7;
    const int wr   = wv >> 1;
    const int wc   = wv & 1;
    const int m0 = blockIdx.x * 128;
    const int n0 = blockIdx.y * 64;

    f32x4 acc[4][2];
    #pragma unroll
    for (int i = 0; i < 4; ++i)
        #pragma unroll
        for (int j = 0; j < 2; ++j)
            acc[i][j] = (f32x4){0.f, 0.f, 0.f, 0.f};

    const int sRow = lane >> 3;                     // 8 rows x 8 chunks per instr
    const int sCh  = (lane & 7) ^ (sRow & 7);       // pre-swizzled chunk

    auto issue = [&](short* Abuf, short* Bbuf, int k0) {
        #pragma unroll
        for (int g = 0; g < 4; ++g) {               // A: wave rows [32wv, 32wv+32)
            int row = 32 * wv + 8 * g + sRow;
            const char* src = (const char*)(A + (size_t)(m0 + row) * lda + k0) + sCh * 16;
            gload_lds16(src, (char*)Abuf + (32 * wv + 8 * g) * 128);
        }
        #pragma unroll
        for (int g = 0; g < 2; ++g) {               // B: wave rows [16wv, 16wv+16)
            int row = 16 * wv + 8 * g + sRow;
            const char* src = (const char*)(B + (size_t)(n0 + row) * ldb + k0) + sCh * 16;
            gload_lds16(src, (char*)Bbuf + (16 * wv + 8 * g) * 128);
        }
    };
    auto compute = [&](const short* Abuf, const short* Bbuf) {
        __builtin_amdgcn_s_setprio(1);
        #pragma unroll
        for (int ks = 0; ks < 2; ++ks) {
            bf16x8 af[4], bfr[2];
            int slot = ((ks * 4 + quad) ^ swz) * 16;
            #pragma unroll
            for (int t = 0; t < 4; ++t)
                af[t] = *(const bf16x8*)((const char*)Abuf + (wr * 64 + t * 16 + c16) * 128 + slot);
            #pragma unroll
            for (int t = 0; t < 2; ++t)
                bfr[t] = *(const bf16x8*)((const char*)Bbuf + (wc * 32 + t * 16 + c16) * 128 + slot);
            #pragma unroll
            for (int tm = 0; tm < 4; ++tm)
                #pragma unroll
                for (int tn = 0; tn < 2; ++tn)
                    acc[tm][tn] = mfma16x16(af[tm], bfr[tn], acc[tm][tn]);
        }
        __builtin_amdgcn_s_setprio(0);
    };

    const int nt = K >> 6;   // 16 (even)
    issue(As[0], Bs[0], 0);
    __syncthreads();

    #pragma unroll 1
    for (int t = 0; t < nt; t += 2) {
        if (t + 1 < nt) issue(As[1], Bs[1], (t + 1) << 6);
        compute(As[0], Bs[0]);
        __syncthreads();
        if (t + 1 < nt) {
            if (t + 2 < nt) issue(As[0], Bs[0], (t + 2) << 6);
            compute(As[1], Bs[1]);
            __syncthreads();
        }
    }

    #pragma unroll
    for (int tm = 0; tm < 4; ++tm) {
        #pragma unroll
        for (int rr = 0; rr < 4; ++rr) {
            int row = m0 + wr * 64 + tm * 16 + quad * 4 + rr;
            float mk = rowmask ? rowmask[row] : 1.0f;
            float rbv = BIASROW ? bias[row] : 0.0f;
            #pragma unroll
            for (int tn = 0; tn < 2; ++tn) {
                int col = n0 + wc * 32 + tn * 16 + c16;
                float b = BIASROW ? rbv : bias[col];
                float val = (acc[tm][tn][rr] + b) * scale;
                if (relu) val = fmaxf(val, 0.0f);
                val *= mk;
                C[(size_t)row * ldc + col] = (OutT)val;
            }
        }
    }
}

// ---- scores -> mask (unchanged)
__global__ void score_mask_kernel(const __bf16* __restrict__ h,
                                  const float* __restrict__ w2,
                                  const float* __restrict__ b2,
                                  float* __restrict__ maskf)
{
    int lane = threadIdx.x & 63;
    int tok  = blockIdx.x * 4 + (threadIdx.x >> 6);
    const __bf16* hr = h + (size_t)tok * 256;
    float s = 0.f;
    #pragma unroll
    for (int j = 0; j < 4; ++j) {
        int c = j * 64 + lane;
        s += (float)hr[c] * w2[c];
    }
    #pragma unroll
    for (int o = 1; o < 64; o <<= 1) s += __shfl_xor(s, o);
    if (lane == 0) {
        float x = s + b2[0];
        maskf[tok] = (x > -1.7346010553881064f) ? 1.0f : 0.0f;
    }
}

// ---- flash attention, QBLK=128 (8 waves, 512 thr), K/V double-buffered
// prefetch: issue(t+1) -> compute(t) -> ONE barrier (drain overlapped).
// Grid 256 = (32 qb, 4 head, 2 ksp), XCD-clustered: all 32 qb-blocks of one
// (head,ksp) group share one XCD's L2. LDS 144 KB -> 1 block/CU, 8 waves.
__global__ __launch_bounds__(512, 1)
void attn_kernel(const __bf16* __restrict__ qp, const __bf16* __restrict__ kp,
                 const __bf16* __restrict__ vpT, const float* __restrict__ maskf,
                 __bf16* __restrict__ O0, __bf16* __restrict__ O1,
                 float* __restrict__ lbuf)
{
    __shared__ __align__(16) short Ks[2][64 * 256];    // 64 KB
    __shared__ __align__(16) short Vs[2][256 * 64];    // 64 KB
    __shared__ __align__(16) short PsA[8 * 16 * 64];   // 16 KB

    const int tid  = threadIdx.x;
    const int lane = tid & 63;
    const int wv   = tid >> 6;       // 0..7
    const int c16  = lane & 15;
    const int quad = lane >> 4;
    const int swz  = c16 & 7;

    const int d    = blockIdx.x;                 // 0..255, XCD = d & 7
    const int orig = ((d & 7) << 5) | (d >> 3);  // bijective: 8 groups x 32
    const int qb   = orig & 31;
    const int head = (orig >> 5) & 3;
    const int ksp  = orig >> 7;
    const int kbase = ksp * 2048;
    const int kend  = kbase + 2048;
    const int q0   = qb * 128 + wv * 16;
    short* Ps = PsA + wv * 16 * 64;
    __bf16* Ob = ksp ? O1 : O0;

    // Q fragments (A-layout: m = lane&15, k = quad*8+j); qp pre-scaled by 1/16
    bf16x8 qf[8];
    #pragma unroll
    for (int c = 0; c < 8; ++c)
        qf[c] = *(const bf16x8*)(qp + (size_t)(q0 + c16) * DMODEL + head * DHEAD + c * 32 + quad * 8);

    f32x4 o[16];
    #pragma unroll
    for (int t = 0; t < 16; ++t) o[t] = (f32x4){0.f, 0.f, 0.f, 0.f};
    float psum[4] = {0.f, 0.f, 0.f, 0.f};

    // staging geometry: wave w stages K rows [8w,8w+8) (2 rows/instr),
    // V rows [32w,32w+32) (8 rows/instr)
    const int kRow0 = wv * 8 + (lane >> 5);
    const int kCh   = lane & 31;
    const int vRow0 = wv * 32 + (lane >> 3);
    const int vCh   = (lane & 7) ^ ((lane >> 3) & 7);

    auto issue = [&](int buf, int n0) {
        #pragma unroll
        for (int g = 0; g < 4; ++g) {
            int key = kRow0 + g * 2;
            int c   = kCh ^ (key & 7);
            const char* src = (const char*)(kp + (size_t)(n0 + key) * DMODEL + head * DHEAD) + c * 16;
            gload_lds16(src, (char*)Ks[buf] + (wv * 8 + g * 2) * 512);
        }
        #pragma unroll
        for (int g = 0; g < 4; ++g) {
            int row = vRow0 + g * 8;
            const char* src = (const char*)(vpT + (size_t)(head * DHEAD + row) * N_TOK + n0) + vCh * 16;
            gload_lds16(src, (char*)Vs[buf] + (wv * 32 + g * 8) * 128);
        }
    };

    issue(0, kbase);
    __syncthreads();
    int cur = 0;

    #pragma unroll 1
    for (int n0 = kbase; n0 < kend; n0 += 64) {
        if (n0 + 64 < kend) issue(cur ^ 1, n0 + 64);
        const short* Kb = Ks[cur];
        const short* Vb = Vs[cur];

        // S = Q K^T
        f32x4 s[4];
        #pragma unroll
        for (int kt = 0; kt < 4; ++kt) s[kt] = (f32x4){0.f, 0.f, 0.f, 0.f};
        __builtin_amdgcn_s_setprio(1);
        #pragma unroll
        for (int c = 0; c < 8; ++c)
            #pragma unroll
            for (int kt = 0; kt < 4; ++kt) {
                bf16x8 bfr = *(const bf16x8*)(&Kb[(kt * 16 + c16) * 256 + (((c * 4 + quad) ^ swz) << 3)]);
                s[kt] = mfma16x16(qf[c], bfr, s[kt]);
            }
        __builtin_amdgcn_s_setprio(0);

        // p = exp(s + maskbias); per-lane denominator; store P swizzled
        #pragma unroll
        for (int kt = 0; kt < 4; ++kt) {
            float biasv = (maskf[n0 + kt * 16 + c16] - 1.0f) * 1e9f;
            #pragma unroll
            for (int r = 0; r < 4; ++r) {
                float p = __expf(s[kt][r] + biasv);
                psum[r] += p;
                int qrow = quad * 4 + r;
                int ch = (kt * 2 + (c16 >> 3)) ^ (qrow & 7);
                *(__bf16*)&Ps[qrow * 64 + ch * 8 + swz] = (__bf16)p;
            }
        }

        __builtin_amdgcn_s_waitcnt(0xc07f);  // lgkmcnt(0): own-wave Ps visible

        // O += P @ V
        __builtin_amdgcn_s_setprio(1);
        #pragma unroll
        for (int kstep = 0; kstep < 2; ++kstep) {
            bf16x8 pf = *(const bf16x8*)(&Ps[c16 * 64 + (((kstep * 4 + quad) ^ swz) << 3)]);
            #pragma unroll
            for (int t = 0; t < 16; ++t) {
                bf16x8 vf = *(const bf16x8*)(&Vb[(t * 16 + c16) * 64 + (((kstep * 4 + quad) ^ swz) << 3)]);
                o[t] = mfma16x16(pf, vf, o[t]);
            }
        }
        __builtin_amdgcn_s_setprio(0);
        __syncthreads();   // drains next-tile gloads (overlapped w/ compute) + buf reuse
        cur ^= 1;
    }

    float inv[4];
    #pragma unroll
    for (int r = 0; r < 4; ++r) {
        float t = psum[r];
        t += __shfl_xor(t, 1);
        t += __shfl_xor(t, 2);
        t += __shfl_xor(t, 4);
        t += __shfl_xor(t, 8);
        if (c16 == 0)
            lbuf[(size_t)(ksp * NHEAD + head) * N_TOK + q0 + quad * 4 + r] = t;
        inv[r] = 1.0f / t;
    }
    #pragma unroll
    for (int t = 0; t < 16; ++t)
        #pragma unroll
        for (int r = 0; r < 4; ++r) {
            float val = o[t][r] * inv[r];
            Ob[(size_t)(q0 + quad * 4 + r) * DMODEL + head * DHEAD + t * 16 + c16] = (__bf16)val;
        }
}

// ---- combine: ctx = (l0*O0 + l1*O1) / (l0+l1); exact (shared m=0)
__global__ void combine_kernel(const __bf16* __restrict__ O0,
                               const __bf16* __restrict__ O1,
                               const float* __restrict__ lbuf,
                               __bf16* __restrict__ out)
{
    int idx  = blockIdx.x * 256 + threadIdx.x;
    int tok  = idx >> 7;
    int g    = idx & 127;
    int head = g >> 5;
    float a = lbuf[(size_t)head * N_TOK + tok];
    float b = lbuf[(size_t)(NHEAD + head) * N_TOK + tok];
    float w0 = a / (a + b);
    float w1 = 1.0f - w0;
    size_t off = (size_t)tok * DMODEL + g * 8;
    bf16x8 x = *(const bf16x8*)(O0 + off);
    bf16x8 y = *(const bf16x8*)(O1 + off);
    bf16x8 z;
    #pragma unroll
    for (int j = 0; j < 8; ++j) z[j] = (__bf16)(w0 * (float)x[j] + w1 * (float)y[j]);
    *(bf16x8*)(out + off) = z;
}

extern "C" void kernel_launch(void* const* d_in, const int* in_sizes, int n_in,
                              void* d_out, int out_size, void* d_ws, size_t ws_size,
                              hipStream_t stream)
{
    (void)in_sizes; (void)n_in; (void)out_size;
    const float* q  = (const float*)d_in[0];
    const float* k  = (const float*)d_in[1];
    const float* v  = (const float*)d_in[2];
    const float* w1 = (const float*)d_in[3];
    const float* b1 = (const float*)d_in[4];
    const float* w2 = (const float*)d_in[5];
    const float* b2 = (const float*)d_in[6];
    const float* wq = (const float*)d_in[7];
    const float* bq = (const float*)d_in[8];
    const float* wk = (const float*)d_in[9];
    const float* bk = (const float*)d_in[10];
    const float* wvw = (const float*)d_in[11];
    const float* bv = (const float*)d_in[12];
    const float* wo = (const float*)d_in[13];
    const float* bo = (const float*)d_in[14];

    // layout: base (35,667,968) + O1 (8 MB) + lbuf (128 KB); split path proven
    // active every round, so require the full footprint.
    if (ws_size < 35667968u + 8388608u + 131072u) return;

    char* ws = (char*)d_ws;
    float*  maskf = (float*)ws;                       // 16 KB
    __bf16* hbuf  = (__bf16*)(ws + 16384);            // 2 MB; reused as woT after score_mask
    __bf16* qp    = (__bf16*)(ws + 16384 + 2097152);  // 8 MB each
    __bf16* kpb   = qp  + 4194304;
    __bf16* vpT   = kpb + 4194304;                    // [1024][4096] via swapped V-gemm
    __bf16* ctx   = vpT + 4194304;                    // also O0; kbf scratch before attn
    __bf16* O1    = (__bf16*)(ws + 35667968u);        // 8 MB; qbf scratch before attn
    float*  lbuf  = (float*)(ws + 35667968u + 8388608u);

    // d_out (16 MB fp32) scratch, all dead before the final GEMM overwrites it:
    // wqT @0 (2MB) | wkT @2MB | wvT @4MB | w1T @6MB (0.5MB) | vbf @6.5MB (8MB)
    __bf16* wqT = (__bf16*)d_out;
    __bf16* wkT = wqT + 1048576;
    __bf16* wvT = wkT + 1048576;
    __bf16* w1T = wvT + 1048576;
    __bf16* vbf = (__bf16*)((char*)d_out + 6815744u);
    __bf16* woT = hbuf;                               // reuses hbuf after score_mask
    __bf16* qbf = O1;                                 // dead until attn writes O1
    __bf16* kbf = ctx;                                // dead until attn writes O0

    // 0) q,k,v -> bf16 (one launch)
    CvtArgs ca;
    ca.src[0] = q;  ca.dst[0] = qbf;
    ca.src[1] = k;  ca.dst[1] = kbf;
    ca.src[2] = v;  ca.dst[2] = vbf;
    cvt_bf16_kernel<<<dim3(2048, 3), 256, 0, stream>>>(ca);

    // 1) transpose w1,wq,wk,wv (one launch; woT must wait for score_mask)
    TWArgs ta;
    ta.src[0] = w1;  ta.dst[0] = w1T;  ta.C[0] = 256;
    ta.src[1] = wq;  ta.dst[1] = wqT;  ta.C[1] = 1024;
    ta.src[2] = wk;  ta.dst[2] = wkT;  ta.C[2] = 1024;
    ta.src[3] = wvw; ta.dst[3] = wvT;  ta.C[3] = 1024;
    transposew_batch_kernel<<<dim3(16, 16, 4), 256, 0, stream>>>(ta);

    // 2) h = relu(q@w1+b1) -> mask
    gemm_bt<__bf16, false><<<dim3(32, 4), 256, 0, stream>>>(
        qbf, 1024, w1T, 1024, b1, hbuf, 256, 1.0f, 1, nullptr, 1024);
    score_mask_kernel<<<1024, 256, 0, stream>>>(hbuf, w2, b2, maskf);

    // 3) wo^T (into hbuf, free now)
    transposew_kernel<<<dim3(16, 16), 256, 0, stream>>>(wo, woT, 1024);

    // 4) projections: qp = (q@wq)/16, kp = k@wk; vpT = (v@wv)^T via operand swap
    gemm_bt<__bf16, false><<<dim3(32, 16), 256, 0, stream>>>(
        qbf, 1024, wqT, 1024, bq, qp, 1024, 0.0625f, 0, nullptr, 1024);
    gemm_bt<__bf16, false><<<dim3(32, 16), 256, 0, stream>>>(
        kbf, 1024, wkT, 1024, bk, kpb, 1024, 1.0f, 0, nullptr, 1024);
    gemm_bt<__bf16, true><<<dim3(8, 64), 256, 0, stream>>>(
        wvT, 1024, vbf, 1024, bv, vpT, 4096, 1.0f, 0, nullptr, 1024);

    // 5) attention (256 blocks, 512 thr, dbuf prefetch, XCD-clustered)
    attn_kernel<<<dim3(256), 512, 0, stream>>>(qp, kpb, vpT, maskf, ctx, O1, lbuf);
    combine_kernel<<<2048, 256, 0, stream>>>(ctx, O1, lbuf, ctx);

    // 6) out-projection
    gemm_bt<float, false><<<dim3(32, 16), 256, 0, stream>>>(
        ctx, 1024, woT, 1024, bo, (float*)d_out, 1024, 1.0f, 0, maskf, 1024);
}